// Round 6
// baseline (35.778 us; speedup 1.0000x reference)
//
#include <hip/hip_runtime.h>
#include <math.h>

#define NA 512
#define NQC 8
#define REP 2   // diagnostic: double the pair-loop work, scale by 0.5 (exact)

#define NCf ((float)(90.4756 / 6.28318530717958647692))
#define A_ERF 0.70710678118654752f      // 1/sqrt(2)
#define G_COEF 0.79788456080286536f     // sqrt(2/pi)

// ---------------- pack kernel: moments -> 3 transposed float4 planes ----------------
__global__ void pack_kernel(const float* __restrict__ q,
                            const float* __restrict__ r,
                            const float* __restrict__ u,
                            const float* __restrict__ quad,
                            float4* __restrict__ pa,
                            float4* __restrict__ pb,
                            float4* __restrict__ pc,
                            float4* __restrict__ r4,
                            float* __restrict__ out) {
    const int idx = blockIdx.x * blockDim.x + threadIdx.x;   // 0..4095
    if (idx == 0) out[0] = 0.0f;                             // pot accumulator init
    if (idx < NA) {
        r4[idx] = make_float4(r[idx*3+0], r[idx*3+1], r[idx*3+2], 0.0f);
    }
    if (idx >= NA * NQC) return;
    const int i = idx >> 3, qch = idx & 7;                   // quad is [i][qch][3][3]
    const float* Q = quad + (size_t)idx * 9;
    const float xx = Q[0], yy = Q[4], zz = Q[8];
    const float xy = 0.5f * (Q[1] + Q[3]);
    const float xz = 0.5f * (Q[2] + Q[6]);
    const float yz = 0.5f * (Q[5] + Q[7]);
    const float tq = xx + yy + zz;
    const int t = qch * NA + i;
    pa[t] = make_float4(q[idx], tq, u[idx*3+0], u[idx*3+1]);
    pb[t] = make_float4(u[idx*3+2], xx, yy, zz);
    pc[t] = make_float4(xy, xz, yz, 0.0f);
}

// ---------------- main kernel (R5 body, REP'd for diagnostics) ----------------
__global__ __launch_bounds__(512)
void main_kernel(const float4* __restrict__ pa,
                 const float4* __restrict__ pb,
                 const float4* __restrict__ pc,
                 const float4* __restrict__ r4,
                 const float* __restrict__ qarr,
                 const float* __restrict__ uarr,
                 const float* __restrict__ kaparr,
                 const float* __restrict__ alparr,
                 float* __restrict__ out) {
    const int j    = blockIdx.x;
    const int tid  = threadIdx.x;
    const int w    = tid >> 6;     // wave index == channel
    const int lane = tid & 63;

    const float4 rj = r4[j];
    const float rjx = rj.x, rjy = rj.y, rjz = rj.z;

    const int tj = w * NA + j;
    const float4 sja = pa[tj], sjb = pb[tj], sjc = pc[tj];
    const float jtq = sja.y;
    const float jxx = sjb.y, jyy = sjb.z, jzz = sjb.w;
    const float jxy = sjc.x, jxz = sjc.y, jyz = sjc.z;

    float e0 = 0.f, eph = 0.f;
    float Fx = 0.f, Fy = 0.f, Fz = 0.f;
    float Hx = 0.f, Hy = 0.f, Hz = 0.f;
    float pQQ = 0.f;

    #pragma unroll 1
    for (int rep = 0; rep < REP; ++rep) {
        #pragma unroll 2
        for (int k = 0; k < 8; ++k) {
            const int i = k * 64 + lane;
            const float4 ri = r4[i];
            const float dx = rjx - ri.x, dy = rjy - ri.y, dz = rjz - ri.z;
            float r2 = dx*dx + dy*dy + dz*dz;
            const bool diag = (i == j);
            if (diag) r2 = 1.0f;
            const float ir  = rsqrtf(r2);
            const float rr  = r2 * ir;
            const float x   = A_ERF * rr;
            const float E2  = __expf(-0.5f * r2);         // == exp(-x*x)
            const float G   = G_COEF * E2;
            const float t   = __builtin_amdgcn_rcpf(fmaf(0.3275911f, x, 1.0f));
            const float pol = t*(0.254829592f + t*(-0.284496736f + t*(1.421413741f
                             + t*(-1.453152027f + t*1.061405429f))));
            const float E   = fmaf(-pol, E2, 1.0f);
            const float ir2 = ir * ir;
            const float ir4 = ir2 * ir2;
            const float g   = E * ir;
            const float GmG = G - g;
            const float nco = diag ? 0.0f : NCf;
            const float c0 = nco * g;
            const float c1 = nco * ir2 * GmG;
            const float c2 = nco * ir2 * (-3.0f*ir2*GmG - G);
            const float c3 = nco * ir2 * (15.0f*ir4*GmG + 5.0f*G*ir2 + G);
            const float c4 = nco * ir2 * (-105.0f*ir4*ir2*GmG - 35.0f*G*ir4 - 7.0f*G*ir2 - G);

            const int tix = w * NA + i;
            const float4 ma = pa[tix], mb = pb[tix], mc = pc[tix];
            const float qi = ma.x, tqi = ma.y, ux = ma.z, uy = ma.w;
            const float uz = mb.x, xx = mb.y, yy = mb.z, zz = mb.w;
            const float xy = mc.x, xz = mc.y, yz = mc.z;

            const float ud  = ux*dx + uy*dy + uz*dz;
            const float Pdx = xx*dx + xy*dy + xz*dz;
            const float Pdy = xy*dx + yy*dy + yz*dz;
            const float Pdz = xz*dx + yz*dy + zz*dz;
            const float Pdd = Pdx*dx + Pdy*dy + Pdz*dz;

            const float t0 = c0 * qi;
            e0  += t0;
            eph += t0 - c1*ud + 0.5f*(c2*Pdd + c1*tqi);

            const float cH = 0.5f*(c2*(ud - tqi) - c3*Pdd);
            const float cF = cH + 0.5f*c2*ud - c1*qi;
            const float c1h = 0.5f * c1;
            Fx += cF*dx + c1*ux - c2*Pdx;
            Fy += cF*dy + c1*uy - c2*Pdy;
            Fz += cF*dz + c1*uz - c2*Pdz;
            Hx += cH*dx + c1h*ux - c2*Pdx;
            Hy += cH*dy + c1h*uy - c2*Pdy;
            Hz += cH*dz + c1h*uz - c2*Pdz;

            const float Rdx = jxx*dx + jxy*dy + jxz*dz;
            const float Rdy = jxy*dx + jyy*dy + jyz*dz;
            const float Rdz = jxz*dx + jyz*dy + jzz*dz;
            const float Rdd = Rdx*dx + Rdy*dy + Rdz*dz;
            const float dPR = Pdx*Rdx + Pdy*Rdy + Pdz*Rdz;
            const float frob = xx*jxx + yy*jyy + zz*jzz + 2.0f*(xy*jxy + xz*jxz + yz*jyz);
            pQQ += c4*(Pdd*Rdd)
                 + c3*(jtq*Pdd + tqi*Rdd + 4.0f*dPR)
                 + c2*(tqi*jtq + 2.0f*frob);
        }
        // prevent cross-rep FP folding; keeps both passes' work real
        asm volatile("" : "+v"(e0), "+v"(eph), "+v"(Fx), "+v"(Fy), "+v"(Fz),
                          "+v"(Hx), "+v"(Hy), "+v"(Hz), "+v"(pQQ));
    }

    const float sc = 1.0f / (float)REP;   // exact power of two
    float acc[9] = {e0*sc, eph*sc, Fx*sc, Fy*sc, Fz*sc, Hx*sc, Hy*sc, Hz*sc, pQQ*sc};
    #pragma unroll
    for (int off = 1; off < 64; off <<= 1) {
        #pragma unroll
        for (int c = 0; c < 9; ++c) acc[c] += __shfl_xor(acc[c], off, 64);
    }

    __shared__ float pl[8];
    if (lane == 0) {
        const float te0 = acc[0], teph = acc[1];
        const float tFx = acc[2], tFy = acc[3], tFz = acc[4];
        const float tHx = acc[5], tHy = acc[6], tHz = acc[7];
        const float tQQ = acc[8] * 0.125f;
        const int jq = j * NQC + w;
        const float qj  = qarr[jq];
        const float ujx = uarr[jq*3+0], ujy = uarr[jq*3+1], ujz = uarr[jq*3+2];
        const float kapv = kaparr[jq];
        const float alpv = alparr[jq];

        pl[w] = qj * (teph - 0.5f*te0)
              - (ujx*tHx + ujy*tHy + ujz*tHz)
              + tQQ
              - 0.5f * kapv * teph * teph
              - 0.5f * alpv * (tFx*tFx + tFy*tFy + tFz*tFz);

        out[1 + jq] = -kapv * teph;
        out[1 + NA*NQC + jq*3 + 0] = alpv * tFx;
        out[1 + NA*NQC + jq*3 + 1] = alpv * tFy;
        out[1 + NA*NQC + jq*3 + 2] = alpv * tFz;
    }
    __syncthreads();
    if (tid == 0) {
        float s = 0.f;
        #pragma unroll
        for (int c = 0; c < 8; ++c) s += pl[c];
        atomicAdd(out, s);
    }
}

extern "C" void kernel_launch(void* const* d_in, const int* in_sizes, int n_in,
                              void* d_out, int out_size, void* d_ws, size_t ws_size,
                              hipStream_t stream) {
    const float* q    = (const float*)d_in[0];
    const float* r    = (const float*)d_in[1];
    const float* u    = (const float*)d_in[4];
    const float* quad = (const float*)d_in[5];
    const float* kap  = (const float*)d_in[6];
    const float* alp  = (const float*)d_in[7];
    float* out = (float*)d_out;
    float* ws  = (float*)d_ws;

    const size_t plane = (size_t)NA * NQC;   // float4 count per plane (4096)
    float4* pa = (float4*)ws;
    float4* pb = pa + plane;
    float4* pc = pb + plane;
    float4* r4 = pc + plane;
    (void)ws_size; (void)in_sizes; (void)n_in; (void)out_size;

    pack_kernel<<<16, 256, 0, stream>>>(q, r, u, quad, pa, pb, pc, r4, out);
    main_kernel<<<NA, 512, 0, stream>>>(pa, pb, pc, r4, q, u, kap, alp, out);
}

// Round 7
// 25.934 us; speedup vs baseline: 1.3796x; 1.3796x over previous
//
#include <hip/hip_runtime.h>
#include <math.h>

#define NA 512
#define NQC 8

#define NCf ((float)(90.4756 / 6.28318530717958647692))
#define A_ERF 0.70710678118654752f      // 1/sqrt(2)
#define G_COEF 0.79788456080286536f     // sqrt(2/pi)

// ---------------- single main kernel ----------------
// grid = 512 blocks (receiver j), block = 512 threads.
// tid = seg*8 + qch; at iter k thread reads source i = k*64 + seg, channel qch.
// => iq = i*8+qch = k*512 + tid: block-wide reads of q/u/quad are CONTIGUOUS
// in the raw input layout — no pack kernel needed.
__global__ __launch_bounds__(512)
void main_kernel(const float* __restrict__ qarr,
                 const float* __restrict__ rarr,
                 const float* __restrict__ uarr,
                 const float* __restrict__ quadarr,
                 const float* __restrict__ kaparr,
                 const float* __restrict__ alparr,
                 float* __restrict__ out) {
    const int j    = blockIdx.x;
    const int tid  = threadIdx.x;
    const int qch  = tid & 7;
    const int seg  = tid >> 3;     // 0..63

    const float rjx = rarr[j*3+0], rjy = rarr[j*3+1], rjz = rarr[j*3+2];

    // receiver symmetric quadrupole for this thread's channel
    const int jq = j * NQC + qch;
    const float* Qj = quadarr + (size_t)jq * 9;
    const float jxx = Qj[0], jyy = Qj[4], jzz = Qj[8];
    const float jxy = 0.5f*(Qj[1]+Qj[3]);
    const float jxz = 0.5f*(Qj[2]+Qj[6]);
    const float jyz = 0.5f*(Qj[5]+Qj[7]);
    const float jtq = jxx + jyy + jzz;

    float e0 = 0.f, eph = 0.f;
    float Fx = 0.f, Fy = 0.f, Fz = 0.f;
    float Hx = 0.f, Hy = 0.f, Hz = 0.f;
    float pQQ = 0.f;

    #pragma unroll 2
    for (int k = 0; k < 8; ++k) {
        const int i  = k * 64 + seg;
        const int iq = k * 512 + tid;          // == i*NQC + qch  (contiguous!)

        const float dx = rjx - rarr[i*3+0];
        const float dy = rjy - rarr[i*3+1];
        const float dz = rjz - rarr[i*3+2];
        float r2 = dx*dx + dy*dy + dz*dz;
        const bool diag = (i == j);
        if (diag) r2 = 1.0f;
        const float ir  = rsqrtf(r2);
        const float rr  = r2 * ir;
        // branch-free erf(rr/sqrt(2)) — A&S 7.1.26, exp shared with G
        const float x   = A_ERF * rr;
        const float E2  = __expf(-0.5f * r2);  // == exp(-x*x)
        const float G   = G_COEF * E2;
        const float t   = __builtin_amdgcn_rcpf(fmaf(0.3275911f, x, 1.0f));
        const float pol = t*(0.254829592f + t*(-0.284496736f + t*(1.421413741f
                         + t*(-1.453152027f + t*1.061405429f))));
        const float E   = fmaf(-pol, E2, 1.0f);
        const float ir2 = ir * ir;
        const float ir4 = ir2 * ir2;
        const float g   = E * ir;
        const float GmG = G - g;
        const float nco = diag ? 0.0f : NCf;
        const float c0 = nco * g;
        const float c1 = nco * ir2 * GmG;
        const float c2 = nco * ir2 * (-3.0f*ir2*GmG - G);
        const float c3 = nco * ir2 * (15.0f*ir4*GmG + 5.0f*G*ir2 + G);
        const float c4 = nco * ir2 * (-105.0f*ir4*ir2*GmG - 35.0f*G*ir4 - 7.0f*G*ir2 - G);

        // raw per-channel source moments (contiguous block-wide)
        const float qi = qarr[iq];
        const float ux = uarr[iq*3+0], uy = uarr[iq*3+1], uz = uarr[iq*3+2];
        const float* Qi = quadarr + (size_t)iq * 9;
        const float xx = Qi[0], yy = Qi[4], zz = Qi[8];
        const float xy = 0.5f*(Qi[1]+Qi[3]);
        const float xz = 0.5f*(Qi[2]+Qi[6]);
        const float yz = 0.5f*(Qi[5]+Qi[7]);
        const float tqi = xx + yy + zz;

        const float ud  = ux*dx + uy*dy + uz*dz;
        const float Pdx = xx*dx + xy*dy + xz*dz;
        const float Pdy = xy*dx + yy*dy + yz*dz;
        const float Pdz = xz*dx + yz*dy + zz*dz;
        const float Pdd = Pdx*dx + Pdy*dy + Pdz*dz;

        const float t0 = c0 * qi;
        e0  += t0;
        eph += t0 - c1*ud + 0.5f*(c2*Pdd + c1*tqi);

        const float cH = 0.5f*(c2*(ud - tqi) - c3*Pdd);
        const float cF = cH + 0.5f*c2*ud - c1*qi;
        const float c1h = 0.5f * c1;
        Fx += cF*dx + c1*ux - c2*Pdx;
        Fy += cF*dy + c1*uy - c2*Pdy;
        Fz += cF*dz + c1*uz - c2*Pdz;
        Hx += cH*dx + c1h*ux - c2*Pdx;
        Hy += cH*dy + c1h*uy - c2*Pdy;
        Hz += cH*dz + c1h*uz - c2*Pdz;

        const float Rdx = jxx*dx + jxy*dy + jxz*dz;
        const float Rdy = jxy*dx + jyy*dy + jyz*dz;
        const float Rdz = jxz*dx + jyz*dy + jzz*dz;
        const float Rdd = Rdx*dx + Rdy*dy + Rdz*dz;
        const float dPR = Pdx*Rdx + Pdy*Rdy + Pdz*Rdz;
        const float frob = xx*jxx + yy*jyy + zz*jzz + 2.0f*(xy*jxy + xz*jxz + yz*jyz);
        pQQ += c4*(Pdd*Rdd)
             + c3*(jtq*Pdd + tqi*Rdd + 4.0f*dPR)
             + c2*(tqi*jtq + 2.0f*frob);
    }

    // ---- reduction: segs within wave (offsets 8,16,32), then cross-wave LDS ----
    float acc[9] = {e0, eph, Fx, Fy, Fz, Hx, Hy, Hz, pQQ};
    #pragma unroll
    for (int off = 8; off < 64; off <<= 1) {
        #pragma unroll
        for (int c = 0; c < 9; ++c) acc[c] += __shfl_xor(acc[c], off, 64);
    }
    __shared__ float red[8][8][9];
    const int lane = tid & 63, wv = tid >> 6;   // 8 waves
    if ((lane & 56) == 0) {
        #pragma unroll
        for (int c = 0; c < 9; ++c) red[wv][lane][c] = acc[c];
    }
    __syncthreads();
    if (tid < 8) {
        float v[9];
        #pragma unroll
        for (int c = 0; c < 9; ++c) {
            float s = 0.f;
            #pragma unroll
            for (int w = 0; w < 8; ++w) s += red[w][tid][c];
            v[c] = s;
        }
        const float te0 = v[0], teph = v[1];
        const float tFx = v[2], tFy = v[3], tFz = v[4];
        const float tHx = v[5], tHy = v[6], tHz = v[7];
        const float tQQ = v[8] * 0.125f;
        const int myjq = j * NQC + tid;
        const float qj  = qarr[myjq];
        const float ujx = uarr[myjq*3+0], ujy = uarr[myjq*3+1], ujz = uarr[myjq*3+2];
        const float kapv = kaparr[myjq];
        const float alpv = alparr[myjq];

        float pot = qj * (teph - 0.5f*te0)
                  - (ujx*tHx + ujy*tHy + ujz*tHz)
                  + tQQ
                  - 0.5f * kapv * teph * teph
                  - 0.5f * alpv * (tFx*tFx + tFy*tFy + tFz*tFz);

        out[1 + myjq] = -kapv * teph;
        out[1 + NA*NQC + myjq*3 + 0] = alpv * tFx;
        out[1 + NA*NQC + myjq*3 + 1] = alpv * tFy;
        out[1 + NA*NQC + myjq*3 + 2] = alpv * tFz;

        // reduce pot across the 8 channels (lanes 0..7), one atomic per block
        #pragma unroll
        for (int off = 4; off; off >>= 1) pot += __shfl_xor(pot, off, 8);
        if (tid == 0) atomicAdd(out, pot);
    }
}

extern "C" void kernel_launch(void* const* d_in, const int* in_sizes, int n_in,
                              void* d_out, int out_size, void* d_ws, size_t ws_size,
                              hipStream_t stream) {
    const float* q    = (const float*)d_in[0];
    const float* r    = (const float*)d_in[1];
    const float* u    = (const float*)d_in[4];
    const float* quad = (const float*)d_in[5];
    const float* kap  = (const float*)d_in[6];
    const float* alp  = (const float*)d_in[7];
    float* out = (float*)d_out;
    (void)d_ws; (void)ws_size; (void)in_sizes; (void)n_in; (void)out_size;

    hipMemsetAsync(out, 0, sizeof(float), stream);   // zero pot accumulator
    main_kernel<<<NA, 512, 0, stream>>>(q, r, u, quad, kap, alp, out);
}